// Round 13
// baseline (542.151 us; speedup 1.0000x reference)
//
#include <hip/hip_runtime.h>
#include <math.h>

// Problem constants: S=512, B=32, R=8, H=128, TOP=3, CHL=19, I=20
//
// Pipeline (5 dispatches):
//  kPro1 : transposes (Kir,Vir) + MT = (Qrr^T@Krr)^T  [MT[g][h] = sum_o Qrr[o][h]Krr[o][g]]
//  kPro2 : k,v = x@KirT/VirT then KQ = k@Qir, cb = k.Qib  (fused, block-local dep)
//  kGRU  : 512-step GRU (frozen R8 config, 357 us)
//  kS1   : stage-1 attention, float4 LDS dots, top-3 -> h1, widx, loser-zeroing
//  kS2G  : fused stage-2: per wave 4 pairs; T1 via MT row-per-lane, qk2+softmax+u
//          (kS2c math), out = h1w + u@Vrr-rows. No T1/U/VrrT globals, no barriers.

typedef float v2f __attribute__((ext_vector_type(2)));

// forced packed fp32 FMA: acc.lo += w.lo*h.lo, acc.hi += w.hi*h.hi
#define PKF(acc, w, h) \
    asm("v_pk_fma_f32 %0, %1, %2, %0" : "+v"(acc) : "v"(w), "v"(h))

// ---------------- prologue 1: transposes + MT ----------------
__global__ __launch_bounds__(256) void kPro1(const float* __restrict__ Kir,
        const float* __restrict__ Vir,
        const float* __restrict__ Qrr, const float* __restrict__ Krr,
        float* __restrict__ KirT, float* __restrict__ VirT,
        float* __restrict__ MT) {
    const int bid = blockIdx.x;
    if (bid < 512) {
        int idx = bid * 256 + threadIdx.x;
        if (idx < 65536) {
            int s = idx >> 7, o = idx & 127;
            KirT[idx] = Kir[o * 512 + s];
        } else {
            int j = idx - 65536;
            int s = j >> 7, o = j & 127;
            VirT[j] = Vir[o * 512 + s];
        }
    } else {
        const int g = (bid - 512) * 2 + (threadIdx.x >> 7);
        const int h = threadIdx.x & 127;
        float acc = 0.0f;
#pragma unroll 4
        for (int o = 0; o < 128; ++o) acc += Qrr[o * 128 + h] * Krr[o * 128 + g];
        MT[g * 128 + h] = acc;
    }
}

// ---------------- prologue 2: k,v then KQ,cb (block-local) ----------------
__global__ __launch_bounds__(128) void kPro2(const float* __restrict__ x,
        const float* __restrict__ KirT, const float* __restrict__ VirT,
        const float* __restrict__ Qir, const float* __restrict__ Qib,
        float* __restrict__ vbuf, float* __restrict__ KQ, float* __restrict__ cb) {
    const int b = blockIdx.x / 20, i = blockIdx.x % 20;
    const int o = threadIdx.x;
    if (i == 0) {  // null channel: everything zero
        vbuf[(b * 20) * 128 + o] = 0.0f;
        KQ[(b * 20) * 128 + o] = 0.0f;
        if (o == 0) cb[b * 20] = 0.0f;
        return;
    }
    __shared__ float xL[512];
    __shared__ float kL[128];
    for (int idx = o; idx < 512; idx += 128)
        xL[idx] = x[(b * 19 + (i - 1)) * 512 + idx];
    __syncthreads();
    float ak = 0.0f, av = 0.0f;
#pragma unroll 4
    for (int s = 0; s < 512; ++s) {
        float xv = xL[s];
        ak += xv * KirT[s * 128 + o];
        av += xv * VirT[s * 128 + o];
    }
    vbuf[(b * 20 + i) * 128 + o] = av;
    kL[o] = ak;
    __syncthreads();
    float acc = 0.0f;
#pragma unroll 4
    for (int p = 0; p < 128; ++p) acc += kL[p] * Qir[p * 128 + o];
    KQ[(b * 20 + i) * 128 + o] = acc;
    if (o == 0) {
        float c = 0.0f;
        for (int p = 0; p < 128; ++p) c += kL[p] * Qib[p];
        cb[b * 20 + i] = c;
    }
}

// ---------------- GRU (frozen R8 configuration) ----------------
template<int CTRL>
__device__ __forceinline__ float dppadd(float v) {
    int r = __builtin_amdgcn_update_dpp(0, __float_as_int(v), CTRL, 0xF, 0xF, true);
    return v + __int_as_float(r);
}
template<int CTRL>
__device__ __forceinline__ float dppbcast(float v) {
    int r = __builtin_amdgcn_update_dpp(0, __float_as_int(v), CTRL, 0xF, 0xF, true);
    return __int_as_float(r);
}

__global__ __launch_bounds__(512, 2) void kGRU(const float* __restrict__ x,
        const float* __restrict__ Wih, const float* __restrict__ Whh,
        float* __restrict__ hs) {
    const int r = blockIdx.x >> 5;
    const int b = blockIdx.x & 31;
    const int t = threadIdx.x;
    const int j = t >> 2;
    const int kq = t & 3;

    __shared__ __align__(16) float xT[512 * 20];    // [s][c], c=0..18 used
    __shared__ __align__(16) float hsBuf[64 * 144]; // 64 rows, swizzled 128+pad

    for (int idx = t; idx < 19 * 512; idx += 512) {
        int c = idx >> 9, s = idx & 511;
        xT[s * 20 + c] = x[(b * 19 + c) * 512 + s];
    }
    if (t < 144) hsBuf[63 * 144 + t] = 0.0f;  // h(-1) = 0

    v2f w0[16], w1[16], w2[16];
    {
        const float* Wb = Whh + (r * 384) * 128 + kq * 32;
        const v2f* s0p = (const v2f*)(Wb + (j) * 128);
        const v2f* s1p = (const v2f*)(Wb + (j + 128) * 128);
        const v2f* s2p = (const v2f*)(Wb + (j + 256) * 128);
#pragma unroll
        for (int u = 0; u < 16; ++u) {
            w0[u] = s0p[u];
            w1[u] = s1p[u];
            w2[u] = s2p[u];
        }
    }
    v2f wiv[9];
    float wlast;
    if (kq < 3) {
        const float* W = Wih + (r * 384 + (j + 128 * kq)) * 20;
#pragma unroll
        for (int c = 0; c < 9; ++c) wiv[c] = (v2f){W[2*c + 1], W[2*c + 2]};
        wlast = W[19];
    } else {
#pragma unroll
        for (int c = 0; c < 9; ++c) wiv[c] = (v2f){0.0f, 0.0f};
        wlast = 0.0f;
    }
    __syncthreads();

    const int jmap = j + ((j >> 5) << 2);
    const int cellBase = (b * 8 + r) * 128;
    float hprev = 0.0f;

    for (int s = 0; s < 512; ++s) {
        const int rowR = (s + 63) & 63;
        const v2f* hp2 = (const v2f*)(hsBuf + rowR * 144 + kq * 36);
        v2f hv[16];
#pragma unroll
        for (int u = 0; u < 16; ++u) hv[u] = hp2[u];

        float xp;
        {
            const v2f* xp2 = (const v2f*)(xT + s * 20);
            float x18 = xT[s * 20 + 18];
            v2f xacc = {0.0f, 0.0f};
            PKF(xacc, wiv[0], xp2[0]);
            PKF(xacc, wiv[1], xp2[1]);
            PKF(xacc, wiv[2], xp2[2]);
            PKF(xacc, wiv[3], xp2[3]);
            PKF(xacc, wiv[4], xp2[4]);
            PKF(xacc, wiv[5], xp2[5]);
            PKF(xacc, wiv[6], xp2[6]);
            PKF(xacc, wiv[7], xp2[7]);
            PKF(xacc, wiv[8], xp2[8]);
            xp = xacc[0] + xacc[1] + wlast * x18;
        }

        v2f a0 = {0.0f, 0.0f}, a1 = {0.0f, 0.0f}, a2 = {0.0f, 0.0f};
#pragma unroll
        for (int u = 0; u < 16; ++u) {
            v2f hh = hv[u];
            PKF(a0, w0[u], hh);
            PKF(a1, w1[u], hh);
            PKF(a2, w2[u], hh);
        }
        float p0 = a0[0] + a0[1];
        float p1 = a1[0] + a1[1];
        float p2 = a2[0] + a2[1];

        p0 = dppadd<0xB1>(p0); p1 = dppadd<0xB1>(p1); p2 = dppadd<0xB1>(p2);
        p0 = dppadd<0x4E>(p0); p1 = dppadd<0x4E>(p1); p2 = dppadd<0x4E>(p2);
        float xr = dppbcast<0x00>(xp);
        float xz = dppbcast<0x55>(xp);
        float xn = dppbcast<0xAA>(xp);

        float rg = __builtin_amdgcn_rcpf(1.0f + __expf(-(p0 + xr)));
        float zg = __builtin_amdgcn_rcpf(1.0f + __expf(-(p1 + xz)));
        float a  = xn + rg * p2;
        float ng = 1.0f - 2.0f * __builtin_amdgcn_rcpf(__expf(2.0f * a) + 1.0f);
        float hnew = ng + zg * (hprev - ng);
        hprev = hnew;
        if (kq == 0) hsBuf[(s & 63) * 144 + jmap] = hnew;
        __syncthreads();

        if ((s & 63) == 63) {
            const int sBase = s - 63;
            const int c4 = (t & 31) * 4;
            const int cm = c4 + ((c4 >> 5) << 2);
#pragma unroll
            for (int w = 0; w < 4; ++w) {
                int rr = (t >> 5) + w * 16;
                float4 v = *(const float4*)(hsBuf + rr * 144 + cm);
                *(float4*)(hs + (size_t)(sBase + rr) * 32768 + cellBase + c4) = v;
            }
            __syncthreads();
        }
    }
}

// ---------------- stage 1 ----------------
__global__ __launch_bounds__(256) void kS1(const float* __restrict__ hs,
        const float* __restrict__ KQ, const float* __restrict__ cb,
        const float* __restrict__ vbuf,
        float* __restrict__ h1, int* __restrict__ widx, float* __restrict__ out) {
    const int b = blockIdx.x & 31;
    const int s0 = (blockIdx.x >> 5) * 8;
    const int t = threadIdx.x;
    __shared__ __align__(16) float KQL[20 * 132];
    __shared__ float vL[20 * 128];
    __shared__ float cbL[20];
    __shared__ __align__(16) float hLt[8 * 132];
    __shared__ float qkL[8 * 20];
    __shared__ float sfL[8 * 20];
    __shared__ float s0L[8];
    __shared__ int wselL[3];

    for (int idx = t; idx < 2560; idx += 256) {
        int i = idx >> 7, h = idx & 127;
        KQL[i * 132 + h] = KQ[(b * 20 + i) * 128 + h];
        vL[i * 128 + h] = vbuf[(b * 20 + i) * 128 + h];
    }
    if (t < 20) cbL[t] = cb[b * 20 + t];
    __syncthreads();

    for (int p = 0; p < 8; ++p) {
        const int s = s0 + p;
        {
            int r = t >> 5, h4 = t & 31;
            float4 hv = *(const float4*)(hs + ((s * 32 + b) * 8 + r) * 128 + h4 * 4);
            *(float4*)(hLt + r * 132 + h4 * 4) = hv;
        }
        __syncthreads();
        if (t < 152) {
            int r = t / 19, i = t % 19 + 1;
            const float4* hr4 = (const float4*)(hLt + r * 132);
            const float4* kg4 = (const float4*)(KQL + i * 132);
            float a = 0.0f;
#pragma unroll
            for (int q = 0; q < 32; ++q) {
                float4 hq = hr4[q];
                float4 kq = kg4[q];
                a += hq.x * kq.x;
                a += hq.y * kq.y;
                a += hq.z * kq.z;
                a += hq.w * kq.w;
            }
            qkL[r * 20 + i] = (a + cbL[i]) * 0.08838834764831845f;
        }
        if (t < 8) qkL[t * 20] = 0.0f;
        __syncthreads();
        if (t < 8) {
            float m = -3.4e38f;
            for (int i = 0; i < 20; ++i) m = fmaxf(m, qkL[t * 20 + i]);
            float sum = 0.0f;
            for (int i = 0; i < 20; ++i) {
                float e = expf(qkL[t * 20 + i] - m);
                sfL[t * 20 + i] = e;
                sum += e;
            }
            float inv = 1.0f / sum;
            for (int i = 0; i < 20; ++i) sfL[t * 20 + i] *= inv;
            s0L[t] = sfL[t * 20];
        }
        if (t == 0) {  // same wave as softmax writers: DS program-order suffices
            unsigned chosen = 0;
            for (int n = 0; n < 3; ++n) {
                float best = 3.4e38f; int bi = 0;
                for (int r2 = 0; r2 < 8; ++r2) {
                    if (chosen & (1u << r2)) continue;
                    float v = s0L[r2];
                    if (v < best) { best = v; bi = r2; }
                }
                chosen |= (1u << bi);
                wselL[n] = bi;
                widx[(s * 32 + b) * 3 + n] = bi;
            }
        }
        __syncthreads();
        {
            const int h = t & 127, rq = t >> 7;
            float a0 = 0, a1 = 0, a2 = 0, a3 = 0;
            for (int i = 1; i < 20; ++i) {
                float vv = vL[i * 128 + h];
                a0 += sfL[(rq * 4 + 0) * 20 + i] * vv;
                a1 += sfL[(rq * 4 + 1) * 20 + i] * vv;
                a2 += sfL[(rq * 4 + 2) * 20 + i] * vv;
                a3 += sfL[(rq * 4 + 3) * 20 + i] * vv;
            }
            const int pairBase = (s * 32 + b) * 8;
            float av[4] = {a0, a1, a2, a3};
#pragma unroll
            for (int jj = 0; jj < 4; ++jj) {
                int rim = rq * 4 + jj;
                h1[(pairBase + rim) * 128 + h] = av[jj];
                bool win = (wselL[0] == rim) || (wselL[1] == rim) || (wselL[2] == rim);
                if (!win) out[(pairBase + rim) * 128 + h] = 0.0f;
            }
        }
        __syncthreads();
    }
}

// ---------------- fused stage 2 ----------------
// grid 1024 x 256; wave wv handles pairs p0..p0+3.  Per pair:
//   T1[wr][g]  = sum_h h1[winner][h] * MT[g][h]      (lane g reads MT row g)
//   qk2,softmax,u  (kS2c math, T1 lane-distributed)
//   out[wr][e] = h1[winner][e] + sum_g u[g]*Vrr[e][g] (lane e reads Vrr row e)
// h1-winner rows and u time-share one 6 KB wave-private LDS region; no barriers.
__global__ __launch_bounds__(256) void kS2G(const float* __restrict__ h1,
        const int* __restrict__ widx, const float* __restrict__ MT,
        const float* __restrict__ Vrr, float* __restrict__ out) {
    const int wv = threadIdx.x >> 6;
    const int lane = threadIdx.x & 63;
    const int p0 = blockIdx.x * 16 + wv * 4;
    __shared__ __align__(16) float scr[4][1536];   // 24 KB: [wave][12 rows x 128]
    float* S = scr[wv];

    int wq[4][3];
#pragma unroll
    for (int q = 0; q < 4; ++q)
#pragma unroll
        for (int wr = 0; wr < 3; ++wr)
            wq[q][wr] = widx[(p0 + q) * 3 + wr];

    // phase 1: winner h1 rows -> LDS (wave-private, no barrier needed)
#pragma unroll
    for (int q = 0; q < 4; ++q)
#pragma unroll
        for (int wr = 0; wr < 3; ++wr) {
            const float* src = h1 + ((p0 + q) * 8 + wq[q][wr]) * 128;
            S[(q * 3 + wr) * 128 + lane] = src[lane];
            S[(q * 3 + wr) * 128 + 64 + lane] = src[64 + lane];
        }

    // phase 2: T1 (lane holds T1[wr][lane] in a0, T1[wr][lane+64] in a1)
    float a0[4][3], a1[4][3];
#pragma unroll
    for (int q = 0; q < 4; ++q)
#pragma unroll
        for (int wr = 0; wr < 3; ++wr) { a0[q][wr] = 0.0f; a1[q][wr] = 0.0f; }
#pragma unroll 2
    for (int h4 = 0; h4 < 128; h4 += 4) {
        float4 ma = *(const float4*)(MT + lane * 128 + h4);
        float4 mb = *(const float4*)(MT + (lane + 64) * 128 + h4);
#pragma unroll
        for (int q = 0; q < 4; ++q)
#pragma unroll
            for (int wr = 0; wr < 3; ++wr) {
                float4 u4 = *(const float4*)(S + (q * 3 + wr) * 128 + h4);
                a0[q][wr] += u4.x * ma.x + u4.y * ma.y + u4.z * ma.z + u4.w * ma.w;
                a1[q][wr] += u4.x * mb.x + u4.y * mb.y + u4.z * mb.z + u4.w * mb.w;
            }
    }

    // phase 3: per pair qk2 + softmax + u -> LDS (overwrites h1w region; phase-2 done)
#pragma unroll
    for (int q = 0; q < 4; ++q) {
        float hv0[8], hv1[8];
        const float* hp = h1 + (p0 + q) * 8 * 128;
#pragma unroll
        for (int c = 0; c < 8; ++c) {
            hv0[c] = hp[c * 128 + lane];
            hv1[c] = hp[c * 128 + 64 + lane];
        }
        float pr[3][8];
#pragma unroll
        for (int wr = 0; wr < 3; ++wr)
#pragma unroll
            for (int c = 0; c < 8; ++c)
                pr[wr][c] = a0[q][wr] * hv0[c] + a1[q][wr] * hv1[c];
#pragma unroll
        for (int off = 32; off > 0; off >>= 1)
#pragma unroll
            for (int wr = 0; wr < 3; ++wr)
#pragma unroll
                for (int c = 0; c < 8; ++c)
                    pr[wr][c] += __shfl_xor(pr[wr][c], off, 64);
#pragma unroll
        for (int wr = 0; wr < 3; ++wr) {
            float m = pr[wr][0];
#pragma unroll
            for (int c = 1; c < 8; ++c) m = fmaxf(m, pr[wr][c]);
            float sum = 0.0f;
#pragma unroll
            for (int c = 0; c < 8; ++c) { pr[wr][c] = expf(pr[wr][c] - m); sum += pr[wr][c]; }
            float inv = 1.0f / sum;
            float uu0 = 0.0f, uu1 = 0.0f;
#pragma unroll
            for (int c = 0; c < 8; ++c) {
                float sv = pr[wr][c] * inv;
                uu0 += sv * hv0[c];
                uu1 += sv * hv1[c];
            }
            S[(q * 3 + wr) * 128 + lane] = uu0;
            S[(q * 3 + wr) * 128 + 64 + lane] = uu1;
        }
    }

    // phase 4: out = h1w + u @ Vrr-rows
    float b0[4][3], b1[4][3];
#pragma unroll
    for (int q = 0; q < 4; ++q)
#pragma unroll
        for (int wr = 0; wr < 3; ++wr) { b0[q][wr] = 0.0f; b1[q][wr] = 0.0f; }
#pragma unroll 2
    for (int g4 = 0; g4 < 128; g4 += 4) {
        float4 va = *(const float4*)(Vrr + lane * 128 + g4);
        float4 vb = *(const float4*)(Vrr + (lane + 64) * 128 + g4);
#pragma unroll
        for (int q = 0; q < 4; ++q)
#pragma unroll
            for (int wr = 0; wr < 3; ++wr) {
                float4 u4 = *(const float4*)(S + (q * 3 + wr) * 128 + g4);
                b0[q][wr] += u4.x * va.x + u4.y * va.y + u4.z * va.z + u4.w * va.w;
                b1[q][wr] += u4.x * vb.x + u4.y * vb.y + u4.z * vb.z + u4.w * vb.w;
            }
    }
#pragma unroll
    for (int q = 0; q < 4; ++q)
#pragma unroll
        for (int wr = 0; wr < 3; ++wr) {
            const int base = ((p0 + q) * 8 + wq[q][wr]) * 128;
            out[base + lane] = h1[base + lane] + b0[q][wr];
            out[base + 64 + lane] = h1[base + 64 + lane] + b1[q][wr];
        }
}

extern "C" void kernel_launch(void* const* d_in, const int* in_sizes, int n_in,
                              void* d_out, int out_size, void* d_ws, size_t ws_size,
                              hipStream_t stream) {
    const float* x   = (const float*)d_in[0];
    const float* Wih = (const float*)d_in[1];
    const float* Whh = (const float*)d_in[2];
    const float* Qir = (const float*)d_in[3];
    const float* Qib = (const float*)d_in[4];
    const float* Kir = (const float*)d_in[5];
    const float* Vir = (const float*)d_in[6];
    const float* Qrr = (const float*)d_in[7];
    const float* Krr = (const float*)d_in[8];
    const float* Vrr = (const float*)d_in[9];
    float* out = (float*)d_out;
    float* ws  = (float*)d_ws;

    // ws layout (floats)
    float* hs   = ws;                  // 16777216  (S,B,R,H)
    float* h1   = ws + 16777216;       // 16777216  (S,B,R,H)
    float* KirT = ws + 33554432;       // 65536
    float* VirT = ws + 33619968;       // 65536
    float* vb   = ws + 33783808;       // 81920
    float* KQ   = ws + 33865728;       // 81920
    float* cb   = ws + 33947648;       // 640
    float* MT   = ws + 33948288;       // 16384
    int*   widx = (int*)(ws + 33964672); // 49152 ints (S,B,3)

    (void)in_sizes; (void)n_in; (void)out_size; (void)ws_size;

    kPro1<<<576, 256, 0, stream>>>(Kir, Vir, Qrr, Krr, KirT, VirT, MT);
    kPro2<<<640, 128, 0, stream>>>(x, KirT, VirT, Qir, Qib, vb, KQ, cb);
    kGRU <<<256, 512, 0, stream>>>(x, Wih, Whh, hs);
    kS1  <<<2048, 256, 0, stream>>>(hs, KQ, cb, vb, h1, widx, out);
    kS2G <<<1024, 256, 0, stream>>>(h1, widx, MT, Vrr, out);
}

// Round 14
// 533.983 us; speedup vs baseline: 1.0153x; 1.0153x over previous
//
#include <hip/hip_runtime.h>
#include <math.h>

// Problem constants: S=512, B=32, R=8, H=128, TOP=3, CHL=19, I=20
//
// Pipeline (7 dispatches) -- best measured configuration (R12, 534.6 us):
//  kPro1 : transposes (Kir,Vir,Vrr) + M = Qrr^T@Krr      (fused, independent)
//  kPro2 : k,v = x@KirT/VirT then KQ = k@Qir, cb = k.Qib  (fused, block-local dep)
//  kGRU  : 512-step GRU (frozen R8 config, 357 us -- invariant across 9 variants)
//  kS1   : stage-1 attention, float4 LDS dots, top-3 -> h1, widx, loser-zeroing
//  kG0   : T1 = gather(h1,widx) @ M       (64-row tiles, grid 768)
//  kS2c  : per-pair wave: qk2, softmax, u -> U
//  kG1   : out[winner] = h1[winner] + U @ VrrT (64-row tiles, grid 768)

typedef float v2f __attribute__((ext_vector_type(2)));

// forced packed fp32 FMA: acc.lo += w.lo*h.lo, acc.hi += w.hi*h.hi
#define PKF(acc, w, h) \
    asm("v_pk_fma_f32 %0, %1, %2, %0" : "+v"(acc) : "v"(w), "v"(h))

// ---------------- prologue 1: transposes + M ----------------
__global__ __launch_bounds__(256) void kPro1(const float* __restrict__ Kir,
        const float* __restrict__ Vir, const float* __restrict__ Vrr,
        const float* __restrict__ Qrr, const float* __restrict__ Krr,
        float* __restrict__ KirT, float* __restrict__ VirT,
        float* __restrict__ VrrT, float* __restrict__ M) {
    const int bid = blockIdx.x;
    if (bid < 576) {
        int idx = bid * 256 + threadIdx.x;
        if (idx < 65536) {
            int s = idx >> 7, o = idx & 127;
            KirT[idx] = Kir[o * 512 + s];
        } else if (idx < 131072) {
            int j = idx - 65536;
            int s = j >> 7, o = j & 127;
            VirT[j] = Vir[o * 512 + s];
        } else if (idx < 147456) {
            int j = idx - 131072;
            int g = j >> 7, h = j & 127;
            VrrT[j] = Vrr[h * 128 + g];
        }
    } else {
        const int h = (bid - 576) * 2 + (threadIdx.x >> 7);
        const int g = threadIdx.x & 127;
        float acc = 0.0f;
#pragma unroll 4
        for (int o = 0; o < 128; ++o) acc += Qrr[o * 128 + h] * Krr[o * 128 + g];
        M[h * 128 + g] = acc;
    }
}

// ---------------- prologue 2: k,v then KQ,cb (block-local) ----------------
__global__ __launch_bounds__(128) void kPro2(const float* __restrict__ x,
        const float* __restrict__ KirT, const float* __restrict__ VirT,
        const float* __restrict__ Qir, const float* __restrict__ Qib,
        float* __restrict__ vbuf, float* __restrict__ KQ, float* __restrict__ cb) {
    const int b = blockIdx.x / 20, i = blockIdx.x % 20;
    const int o = threadIdx.x;
    if (i == 0) {  // null channel: everything zero
        vbuf[(b * 20) * 128 + o] = 0.0f;
        KQ[(b * 20) * 128 + o] = 0.0f;
        if (o == 0) cb[b * 20] = 0.0f;
        return;
    }
    __shared__ float xL[512];
    __shared__ float kL[128];
    for (int idx = o; idx < 512; idx += 128)
        xL[idx] = x[(b * 19 + (i - 1)) * 512 + idx];
    __syncthreads();
    float ak = 0.0f, av = 0.0f;
#pragma unroll 4
    for (int s = 0; s < 512; ++s) {
        float xv = xL[s];
        ak += xv * KirT[s * 128 + o];
        av += xv * VirT[s * 128 + o];
    }
    vbuf[(b * 20 + i) * 128 + o] = av;
    kL[o] = ak;
    __syncthreads();
    float acc = 0.0f;
#pragma unroll 4
    for (int p = 0; p < 128; ++p) acc += kL[p] * Qir[p * 128 + o];
    KQ[(b * 20 + i) * 128 + o] = acc;
    if (o == 0) {
        float c = 0.0f;
        for (int p = 0; p < 128; ++p) c += kL[p] * Qib[p];
        cb[b * 20 + i] = c;
    }
}

// ---------------- GRU (frozen R8 configuration) ----------------
template<int CTRL>
__device__ __forceinline__ float dppadd(float v) {
    int r = __builtin_amdgcn_update_dpp(0, __float_as_int(v), CTRL, 0xF, 0xF, true);
    return v + __int_as_float(r);
}
template<int CTRL>
__device__ __forceinline__ float dppbcast(float v) {
    int r = __builtin_amdgcn_update_dpp(0, __float_as_int(v), CTRL, 0xF, 0xF, true);
    return __int_as_float(r);
}

__global__ __launch_bounds__(512, 2) void kGRU(const float* __restrict__ x,
        const float* __restrict__ Wih, const float* __restrict__ Whh,
        float* __restrict__ hs) {
    const int r = blockIdx.x >> 5;
    const int b = blockIdx.x & 31;
    const int t = threadIdx.x;
    const int j = t >> 2;
    const int kq = t & 3;

    __shared__ __align__(16) float xT[512 * 20];    // [s][c], c=0..18 used
    __shared__ __align__(16) float hsBuf[64 * 144]; // 64 rows, swizzled 128+pad

    for (int idx = t; idx < 19 * 512; idx += 512) {
        int c = idx >> 9, s = idx & 511;
        xT[s * 20 + c] = x[(b * 19 + c) * 512 + s];
    }
    if (t < 144) hsBuf[63 * 144 + t] = 0.0f;  // h(-1) = 0

    v2f w0[16], w1[16], w2[16];
    {
        const float* Wb = Whh + (r * 384) * 128 + kq * 32;
        const v2f* s0p = (const v2f*)(Wb + (j) * 128);
        const v2f* s1p = (const v2f*)(Wb + (j + 128) * 128);
        const v2f* s2p = (const v2f*)(Wb + (j + 256) * 128);
#pragma unroll
        for (int u = 0; u < 16; ++u) {
            w0[u] = s0p[u];
            w1[u] = s1p[u];
            w2[u] = s2p[u];
        }
    }
    v2f wiv[9];
    float wlast;
    if (kq < 3) {
        const float* W = Wih + (r * 384 + (j + 128 * kq)) * 20;
#pragma unroll
        for (int c = 0; c < 9; ++c) wiv[c] = (v2f){W[2*c + 1], W[2*c + 2]};
        wlast = W[19];
    } else {
#pragma unroll
        for (int c = 0; c < 9; ++c) wiv[c] = (v2f){0.0f, 0.0f};
        wlast = 0.0f;
    }
    __syncthreads();

    const int jmap = j + ((j >> 5) << 2);
    const int cellBase = (b * 8 + r) * 128;
    float hprev = 0.0f;

    for (int s = 0; s < 512; ++s) {
        const int rowR = (s + 63) & 63;
        const v2f* hp2 = (const v2f*)(hsBuf + rowR * 144 + kq * 36);
        v2f hv[16];
#pragma unroll
        for (int u = 0; u < 16; ++u) hv[u] = hp2[u];

        float xp;
        {
            const v2f* xp2 = (const v2f*)(xT + s * 20);
            float x18 = xT[s * 20 + 18];
            v2f xacc = {0.0f, 0.0f};
            PKF(xacc, wiv[0], xp2[0]);
            PKF(xacc, wiv[1], xp2[1]);
            PKF(xacc, wiv[2], xp2[2]);
            PKF(xacc, wiv[3], xp2[3]);
            PKF(xacc, wiv[4], xp2[4]);
            PKF(xacc, wiv[5], xp2[5]);
            PKF(xacc, wiv[6], xp2[6]);
            PKF(xacc, wiv[7], xp2[7]);
            PKF(xacc, wiv[8], xp2[8]);
            xp = xacc[0] + xacc[1] + wlast * x18;
        }

        v2f a0 = {0.0f, 0.0f}, a1 = {0.0f, 0.0f}, a2 = {0.0f, 0.0f};
#pragma unroll
        for (int u = 0; u < 16; ++u) {
            v2f hh = hv[u];
            PKF(a0, w0[u], hh);
            PKF(a1, w1[u], hh);
            PKF(a2, w2[u], hh);
        }
        float p0 = a0[0] + a0[1];
        float p1 = a1[0] + a1[1];
        float p2 = a2[0] + a2[1];

        p0 = dppadd<0xB1>(p0); p1 = dppadd<0xB1>(p1); p2 = dppadd<0xB1>(p2);
        p0 = dppadd<0x4E>(p0); p1 = dppadd<0x4E>(p1); p2 = dppadd<0x4E>(p2);
        float xr = dppbcast<0x00>(xp);
        float xz = dppbcast<0x55>(xp);
        float xn = dppbcast<0xAA>(xp);

        float rg = __builtin_amdgcn_rcpf(1.0f + __expf(-(p0 + xr)));
        float zg = __builtin_amdgcn_rcpf(1.0f + __expf(-(p1 + xz)));
        float a  = xn + rg * p2;
        float ng = 1.0f - 2.0f * __builtin_amdgcn_rcpf(__expf(2.0f * a) + 1.0f);
        float hnew = ng + zg * (hprev - ng);
        hprev = hnew;
        if (kq == 0) hsBuf[(s & 63) * 144 + jmap] = hnew;
        __syncthreads();

        if ((s & 63) == 63) {
            const int sBase = s - 63;
            const int c4 = (t & 31) * 4;
            const int cm = c4 + ((c4 >> 5) << 2);
#pragma unroll
            for (int w = 0; w < 4; ++w) {
                int rr = (t >> 5) + w * 16;
                float4 v = *(const float4*)(hsBuf + rr * 144 + cm);
                *(float4*)(hs + (size_t)(sBase + rr) * 32768 + cellBase + c4) = v;
            }
            __syncthreads();
        }
    }
}

// ---------------- stage 1 ----------------
__global__ __launch_bounds__(256) void kS1(const float* __restrict__ hs,
        const float* __restrict__ KQ, const float* __restrict__ cb,
        const float* __restrict__ vbuf,
        float* __restrict__ h1, int* __restrict__ widx, float* __restrict__ out) {
    const int b = blockIdx.x & 31;
    const int s0 = (blockIdx.x >> 5) * 8;
    const int t = threadIdx.x;
    __shared__ __align__(16) float KQL[20 * 132];
    __shared__ float vL[20 * 128];
    __shared__ float cbL[20];
    __shared__ __align__(16) float hLt[8 * 132];
    __shared__ float qkL[8 * 20];
    __shared__ float sfL[8 * 20];
    __shared__ float s0L[8];
    __shared__ int wselL[3];

    for (int idx = t; idx < 2560; idx += 256) {
        int i = idx >> 7, h = idx & 127;
        KQL[i * 132 + h] = KQ[(b * 20 + i) * 128 + h];
        vL[i * 128 + h] = vbuf[(b * 20 + i) * 128 + h];
    }
    if (t < 20) cbL[t] = cb[b * 20 + t];
    __syncthreads();

    for (int p = 0; p < 8; ++p) {
        const int s = s0 + p;
        {
            int r = t >> 5, h4 = t & 31;
            float4 hv = *(const float4*)(hs + ((s * 32 + b) * 8 + r) * 128 + h4 * 4);
            *(float4*)(hLt + r * 132 + h4 * 4) = hv;
        }
        __syncthreads();
        if (t < 152) {
            int r = t / 19, i = t % 19 + 1;
            const float4* hr4 = (const float4*)(hLt + r * 132);
            const float4* kg4 = (const float4*)(KQL + i * 132);
            float a = 0.0f;
#pragma unroll
            for (int q = 0; q < 32; ++q) {
                float4 hq = hr4[q];
                float4 kq = kg4[q];
                a += hq.x * kq.x;
                a += hq.y * kq.y;
                a += hq.z * kq.z;
                a += hq.w * kq.w;
            }
            qkL[r * 20 + i] = (a + cbL[i]) * 0.08838834764831845f;
        }
        if (t < 8) qkL[t * 20] = 0.0f;
        __syncthreads();
        if (t < 8) {
            float m = -3.4e38f;
            for (int i = 0; i < 20; ++i) m = fmaxf(m, qkL[t * 20 + i]);
            float sum = 0.0f;
            for (int i = 0; i < 20; ++i) {
                float e = expf(qkL[t * 20 + i] - m);
                sfL[t * 20 + i] = e;
                sum += e;
            }
            float inv = 1.0f / sum;
            for (int i = 0; i < 20; ++i) sfL[t * 20 + i] *= inv;
            s0L[t] = sfL[t * 20];
        }
        if (t == 0) {  // same wave as softmax writers: DS program-order suffices
            unsigned chosen = 0;
            for (int n = 0; n < 3; ++n) {
                float best = 3.4e38f; int bi = 0;
                for (int r2 = 0; r2 < 8; ++r2) {
                    if (chosen & (1u << r2)) continue;
                    float v = s0L[r2];
                    if (v < best) { best = v; bi = r2; }
                }
                chosen |= (1u << bi);
                wselL[n] = bi;
                widx[(s * 32 + b) * 3 + n] = bi;
            }
        }
        __syncthreads();
        {
            const int h = t & 127, rq = t >> 7;
            float a0 = 0, a1 = 0, a2 = 0, a3 = 0;
            for (int i = 1; i < 20; ++i) {
                float vv = vL[i * 128 + h];
                a0 += sfL[(rq * 4 + 0) * 20 + i] * vv;
                a1 += sfL[(rq * 4 + 1) * 20 + i] * vv;
                a2 += sfL[(rq * 4 + 2) * 20 + i] * vv;
                a3 += sfL[(rq * 4 + 3) * 20 + i] * vv;
            }
            const int pairBase = (s * 32 + b) * 8;
            float av[4] = {a0, a1, a2, a3};
#pragma unroll
            for (int jj = 0; jj < 4; ++jj) {
                int rim = rq * 4 + jj;
                h1[(pairBase + rim) * 128 + h] = av[jj];
                bool win = (wselL[0] == rim) || (wselL[1] == rim) || (wselL[2] == rim);
                if (!win) out[(pairBase + rim) * 128 + h] = 0.0f;
            }
        }
        __syncthreads();
    }
}

// ---------------- stage-2 GEMMs (64-row tiles, grid 768) ----------------
// EPI=0: C[n][g] = sum_h h1[pair(n)*8 + widx[n]][h] * Bm[h][g]            (T1)
// EPI=1: out[pair*8+widx[n]][c] = h1[same row][c] + sum_g U[n][g]*Bm[g][c]
template<int EPI>
__global__ __launch_bounds__(256) void kGemm(
        const float* __restrict__ Asrc,
        const float* __restrict__ Bm,
        const int* __restrict__ widx,
        const float* __restrict__ h1g,
        float* __restrict__ C) {
    __shared__ float ALt[64][68];         // [k][row], transposed A chunk (64 rows)
    __shared__ float BL[64][128];         // [k][swizzled col]
    const int n0 = blockIdx.x * 64;
    const int t = threadIdx.x;
    const int tr = t >> 4, tc = t & 15;   // 4 rows x 8 cols micro-tile
    const int q0 = 2 * tc, q1 = 2 * tc + 1;
    const int bq0 = (q0 ^ (q0 >> 3)) * 4;
    const int bq1 = (q1 ^ (q1 >> 3)) * 4;
    float acc[4][8];
#pragma unroll
    for (int i = 0; i < 4; ++i)
#pragma unroll
        for (int jj = 0; jj < 8; ++jj) acc[i][jj] = 0.0f;

    for (int kc = 0; kc < 128; kc += 64) {
        __syncthreads();
        // stage A transposed: 64 rows x 64 k  (1024 float4, 4/thread)
#pragma unroll
        for (int i = 0; i < 4; ++i) {
            int idx = t + i * 256;
            int row = idx >> 4, qk = idx & 15;
            const float* src;
            if (EPI == 0) {
                int n = n0 + row;
                int pair = n / 3;
                int rim = widx[n];
                src = Asrc + ((pair << 3) + rim) * 128 + kc + qk * 4;
            } else {
                src = Asrc + (n0 + row) * 128 + kc + qk * 4;
            }
            float4 a = *(const float4*)src;
            ALt[qk * 4 + 0][row] = a.x;
            ALt[qk * 4 + 1][row] = a.y;
            ALt[qk * 4 + 2][row] = a.z;
            ALt[qk * 4 + 3][row] = a.w;
        }
        // stage B with quad-XOR swizzle
#pragma unroll
        for (int i = 0; i < 8; ++i) {
            int idx = t + i * 256;
            int kk = idx >> 5, qc = idx & 31;
            float4 bv = *(const float4*)(Bm + (kc + kk) * 128 + qc * 4);
            int pos = (qc ^ (qc >> 3)) * 4;
            *(float4*)&BL[kk][pos] = bv;
        }
        __syncthreads();
#pragma unroll 2
        for (int k = 0; k < 64; ++k) {
            float4 a0 = *(const float4*)&ALt[k][4 * tr];
            float4 b0 = *(const float4*)&BL[k][bq0];
            float4 b1 = *(const float4*)&BL[k][bq1];
            float ar[4] = {a0.x, a0.y, a0.z, a0.w};
            float bc[8] = {b0.x, b0.y, b0.z, b0.w, b1.x, b1.y, b1.z, b1.w};
#pragma unroll
            for (int i = 0; i < 4; ++i)
#pragma unroll
                for (int jj = 0; jj < 8; ++jj) acc[i][jj] += ar[i] * bc[jj];
        }
    }
    if (EPI == 0) {
#pragma unroll
        for (int i = 0; i < 4; ++i) {
            int row = n0 + 4 * tr + i;
            *(float4*)(C + row * 128 + 8 * tc) =
                make_float4(acc[i][0], acc[i][1], acc[i][2], acc[i][3]);
            *(float4*)(C + row * 128 + 8 * tc + 4) =
                make_float4(acc[i][4], acc[i][5], acc[i][6], acc[i][7]);
        }
    } else {
#pragma unroll
        for (int i = 0; i < 4; ++i) {
            int n = n0 + 4 * tr + i;
            int pair = n / 3;
            int rim = widx[n];
            int base = ((pair << 3) + rim) * 128 + 8 * tc;
            float4 w0 = *(const float4*)(h1g + base);
            float4 w1 = *(const float4*)(h1g + base + 4);
            *(float4*)(C + base) = make_float4(acc[i][0] + w0.x, acc[i][1] + w0.y,
                                               acc[i][2] + w0.z, acc[i][3] + w0.w);
            *(float4*)(C + base + 4) = make_float4(acc[i][4] + w1.x, acc[i][5] + w1.y,
                                                   acc[i][6] + w1.z, acc[i][7] + w1.w);
        }
    }
}

// ---------------- stage-2 core: qk2 + softmax + u (one wave per pair) ----------------
__global__ __launch_bounds__(256) void kS2c(const float* __restrict__ T1,
        const float* __restrict__ h1, float* __restrict__ U) {
    const int w = threadIdx.x >> 6;
    const int lane = threadIdx.x & 63;
    const int p = blockIdx.x * 4 + w;
    const int base8 = p * 8 * 128;
    float hv0[8], hv1[8];
#pragma unroll
    for (int c = 0; c < 8; ++c) {
        hv0[c] = h1[base8 + c * 128 + lane];
        hv1[c] = h1[base8 + c * 128 + 64 + lane];
    }
    float t0[3], t1v[3];
#pragma unroll
    for (int wr = 0; wr < 3; ++wr) {
        t0[wr]  = T1[(p * 3 + wr) * 128 + lane];
        t1v[wr] = T1[(p * 3 + wr) * 128 + 64 + lane];
    }
    float pr[3][8];
#pragma unroll
    for (int wr = 0; wr < 3; ++wr)
#pragma unroll
        for (int c = 0; c < 8; ++c)
            pr[wr][c] = t0[wr] * hv0[c] + t1v[wr] * hv1[c];
#pragma unroll
    for (int off = 32; off > 0; off >>= 1)
#pragma unroll
        for (int wr = 0; wr < 3; ++wr)
#pragma unroll
            for (int c = 0; c < 8; ++c)
                pr[wr][c] += __shfl_xor(pr[wr][c], off, 64);
#pragma unroll
    for (int wr = 0; wr < 3; ++wr) {
        float m = pr[wr][0];
#pragma unroll
        for (int c = 1; c < 8; ++c) m = fmaxf(m, pr[wr][c]);
        float sum = 0.0f;
#pragma unroll
        for (int c = 0; c < 8; ++c) { pr[wr][c] = expf(pr[wr][c] - m); sum += pr[wr][c]; }
        float inv = 1.0f / sum;
        float u0 = 0.0f, u1 = 0.0f;
#pragma unroll
        for (int c = 0; c < 8; ++c) {
            float sv = pr[wr][c] * inv;
            u0 += sv * hv0[c];
            u1 += sv * hv1[c];
        }
        U[(p * 3 + wr) * 128 + lane] = u0;
        U[(p * 3 + wr) * 128 + 64 + lane] = u1;
    }
}

extern "C" void kernel_launch(void* const* d_in, const int* in_sizes, int n_in,
                              void* d_out, int out_size, void* d_ws, size_t ws_size,
                              hipStream_t stream) {
    const float* x   = (const float*)d_in[0];
    const float* Wih = (const float*)d_in[1];
    const float* Whh = (const float*)d_in[2];
    const float* Qir = (const float*)d_in[3];
    const float* Qib = (const float*)d_in[4];
    const float* Kir = (const float*)d_in[5];
    const float* Vir = (const float*)d_in[6];
    const float* Qrr = (const float*)d_in[7];
    const float* Krr = (const float*)d_in[8];
    const float* Vrr = (const float*)d_in[9];
    float* out = (float*)d_out;
    float* ws  = (float*)d_ws;

    // ws layout (floats)
    float* hs   = ws;                  // 16777216  (S,B,R,H) -- dead after kS1
    float* h1   = ws + 16777216;       // 16777216  (S,B,R,H)
    float* KirT = ws + 33554432;       // 65536
    float* VirT = ws + 33619968;       // 65536
    float* VrrT = ws + 33685504;       // 16384
    float* vb   = ws + 33783808;       // 81920
    float* KQ   = ws + 33865728;       // 81920
    float* cb   = ws + 33947648;       // 640
    float* Mm   = ws + 33948288;       // 16384
    int*   widx = (int*)(ws + 33964672); // 49152 ints (S,B,3)
    // stage-2 temporaries overlap the (dead) hs region:
    float* T1   = ws;                  // 6291456   (49152,128)
    float* U    = ws + 6291456;        // 6291456   (49152,128)

    (void)in_sizes; (void)n_in; (void)out_size; (void)ws_size;

    kPro1<<<640, 256, 0, stream>>>(Kir, Vir, Vrr, Qrr, Krr, KirT, VirT, VrrT, Mm);
    kPro2<<<640, 128, 0, stream>>>(x, KirT, VirT, Qir, Qib, vb, KQ, cb);
    kGRU <<<256, 512, 0, stream>>>(x, Wih, Whh, hs);
    kS1  <<<2048, 256, 0, stream>>>(hs, KQ, cb, vb, h1, widx, out);
    kGemm<0><<<768, 256, 0, stream>>>(h1, Mm, widx, nullptr, T1);
    kS2c <<<4096, 256, 0, stream>>>(T1, h1, U);
    kGemm<1><<<768, 256, 0, stream>>>(U, VrrT, widx, h1, out);
}